// Round 1
// baseline (330.360 us; speedup 1.0000x reference)
//
#include <hip/hip_runtime.h>
#include <hip/hip_bf16.h>

typedef __attribute__((ext_vector_type(8))) short short8;
typedef __attribute__((ext_vector_type(4))) float f32x4;
typedef __attribute__((ext_vector_type(4))) unsigned short u16x4;

#define DEVI static __device__ __forceinline__

constexpr int B_ = 4, S_ = 2048, D_ = 768, NH_ = 12, DH_ = 64;
constexpr int M_ = B_ * S_;                 // 8192
constexpr size_t NX = (size_t)M_ * D_;      // 6291456 elems
constexpr size_t NW = (size_t)D_ * D_;      // 589824 elems

DEVI unsigned short f2bf(float f) {
  union { float f; unsigned u; } c; c.f = f;
  unsigned u = c.u;
  return (unsigned short)((u + 0x7FFFu + ((u >> 16) & 1u)) >> 16);  // RNE
}

DEVI void gload16(const void* g, void* l) {
  __builtin_amdgcn_global_load_lds(
      (const __attribute__((address_space(1))) void*)g,
      (__attribute__((address_space(3))) void*)l, 16, 0, 0);
}

// ---------------------------------------------------------------- convert
__global__ __launch_bounds__(256) void convert_kernel(
    const float* __restrict__ s0, const float* __restrict__ s1,
    const float* __restrict__ s2, const float* __restrict__ s3,
    const float* __restrict__ s4, const float* __restrict__ s5,
    const float* __restrict__ s6,
    unsigned short* __restrict__ d0, unsigned short* __restrict__ d1,
    unsigned short* __restrict__ d2, unsigned short* __restrict__ d3,
    unsigned short* __restrict__ d4, unsigned short* __restrict__ d5,
    unsigned short* __restrict__ d6) {
  int seg = blockIdx.y;
  const float* src; unsigned short* dst; long n;
  switch (seg) {
    case 0: src = s0; dst = d0; n = (long)NX; break;
    case 1: src = s1; dst = d1; n = (long)NX; break;
    case 2: src = s2; dst = d2; n = (long)NX; break;
    case 3: src = s3; dst = d3; n = (long)NW; break;
    case 4: src = s4; dst = d4; n = (long)NW; break;
    case 5: src = s5; dst = d5; n = (long)NW; break;
    default: src = s6; dst = d6; n = (long)NW; break;
  }
  long i = (long)blockIdx.x * 256 + threadIdx.x;
  if (i * 4 >= n) return;
  f32x4 v = *(const f32x4*)(src + i * 4);
  u16x4 o;
  o.x = f2bf(v.x); o.y = f2bf(v.y); o.z = f2bf(v.z); o.w = f2bf(v.w);
  *(u16x4*)(dst + i * 4) = o;
}

// ---------------------------------------------------------------- gemm core
// C[128x128] tile of A[M,768] @ Bt[768,768]^T, bf16 MFMA 16x16x32.
// 4 waves, each 64x64 (4x4 fragments). BK=32, global_load_lds staging.
DEVI void gemm_core(const unsigned short* __restrict__ A,
                    const unsigned short* __restrict__ Bt,
                    unsigned short* As, unsigned short* Bs,
                    int m0, int n0, int tid, f32x4 acc[4][4]) {
  const int w = tid >> 6, l = tid & 63;
  const int wm = w >> 1, wn = w & 1;
  const int lr = l & 15, lg = l >> 4;

  const unsigned short* gA0 = A  + (size_t)(m0 + (tid >> 2)) * 768 + (tid & 3) * 8;
  const unsigned short* gB0 = Bt + (size_t)(n0 + (tid >> 2)) * 768 + (tid & 3) * 8;
  unsigned short* lA0 = As + (size_t)(w * 64) * 8;  // wave-uniform LDS base
  unsigned short* lB0 = Bs + (size_t)(w * 64) * 8;
  const unsigned short* fA = As + (size_t)(wm * 64 + lr) * 32 + lg * 8;
  const unsigned short* fB = Bs + (size_t)(wn * 64 + lr) * 32 + lg * 8;

  for (int k0 = 0; k0 < 768; k0 += 32) {
    __syncthreads();
    gload16(gA0 + k0, lA0);
    gload16(gA0 + (size_t)64 * 768 + k0, lA0 + 2048);
    gload16(gB0 + k0, lB0);
    gload16(gB0 + (size_t)64 * 768 + k0, lB0 + 2048);
    __syncthreads();
    short8 af[4], bf[4];
#pragma unroll
    for (int m = 0; m < 4; m++) af[m] = *(const short8*)(fA + m * 16 * 32);
#pragma unroll
    for (int n = 0; n < 4; n++) bf[n] = *(const short8*)(fB + n * 16 * 32);
#pragma unroll
    for (int m = 0; m < 4; m++)
#pragma unroll
      for (int n = 0; n < 4; n++)
        acc[m][n] = __builtin_amdgcn_mfma_f32_16x16x32_bf16(af[m], bf[n], acc[m][n], 0, 0, 0);
  }
}

// ---------------------------------------------------------------- QKV gemm
__global__ __launch_bounds__(256) void qkv_gemm(
    const unsigned short* __restrict__ Xq, const unsigned short* __restrict__ Xk,
    const unsigned short* __restrict__ Xv,
    const unsigned short* __restrict__ Wq, const unsigned short* __restrict__ Wk,
    const unsigned short* __restrict__ Wv,
    const float* __restrict__ bq, const float* __restrict__ bk,
    const float* __restrict__ bv,
    unsigned short* __restrict__ Oq, unsigned short* __restrict__ Ok,
    unsigned short* __restrict__ Ov) {
  __shared__ unsigned short As[128 * 32], Bs[128 * 32];
  const int z = blockIdx.z;
  const unsigned short* A  = (z == 0) ? Xq : (z == 1) ? Xk : Xv;
  const unsigned short* Bt = (z == 0) ? Wq : (z == 1) ? Wk : Wv;
  const float* bias        = (z == 0) ? bq : (z == 1) ? bk : bv;
  unsigned short* O        = (z == 0) ? Oq : (z == 1) ? Ok : Ov;
  const float scale = (z == 0) ? 0.125f : 1.0f;

  const int m0 = blockIdx.x * 128, n0 = blockIdx.y * 128;
  f32x4 acc[4][4] = {};
  gemm_core(A, Bt, As, Bs, m0, n0, threadIdx.x, acc);

  const int tid = threadIdx.x, w = tid >> 6, l = tid & 63;
  const int wm = w >> 1, wn = w & 1, lr = l & 15, lg = l >> 4;
#pragma unroll
  for (int n = 0; n < 4; n++) {
    const int ng = n0 + wn * 64 + n * 16 + lr;
    const float bvv = bias[ng];
    const int h = ng >> 6, d = ng & 63;
#pragma unroll
    for (int m = 0; m < 4; m++) {
#pragma unroll
      for (int r = 0; r < 4; r++) {
        const int mg = m0 + wm * 64 + m * 16 + lg * 4 + r;
        const int b = mg >> 11, s = mg & 2047;
        O[((size_t)(b * NH_ + h) * S_ + s) * DH_ + d] = f2bf((acc[m][n][r] + bvv) * scale);
      }
    }
  }
}

// ---------------------------------------------------------------- out gemm
__global__ __launch_bounds__(256) void out_gemm(
    const unsigned short* __restrict__ A, const unsigned short* __restrict__ Bt,
    const float* __restrict__ bias, float* __restrict__ out) {
  __shared__ unsigned short As[128 * 32], Bs[128 * 32];
  const int m0 = blockIdx.x * 128, n0 = blockIdx.y * 128;
  f32x4 acc[4][4] = {};
  gemm_core(A, Bt, As, Bs, m0, n0, threadIdx.x, acc);

  const int tid = threadIdx.x, w = tid >> 6, l = tid & 63;
  const int wm = w >> 1, wn = w & 1, lr = l & 15, lg = l >> 4;
#pragma unroll
  for (int n = 0; n < 4; n++) {
    const int ng = n0 + wn * 64 + n * 16 + lr;
    const float bvv = bias[ng];
#pragma unroll
    for (int m = 0; m < 4; m++) {
#pragma unroll
      for (int r = 0; r < 4; r++) {
        const int mg = m0 + wm * 64 + m * 16 + lg * 4 + r;
        out[(size_t)mg * 768 + ng] = acc[m][n][r] + bvv;
      }
    }
  }
}

// ---------------------------------------------------------------- V transpose
// Vp[B,H,S,D] -> Vt[B,H,D,S], per (b,h): [2048][64] -> [64][2048]
__global__ __launch_bounds__(256) void transpose_v(
    const unsigned short* __restrict__ Vp, unsigned short* __restrict__ Vt) {
  __shared__ unsigned short T[64 * 72];
  const int bh = blockIdx.y;
  const int s0 = blockIdx.x * 64;
  const int t = threadIdx.x;
  const int rl = t >> 3, u = t & 7;
#pragma unroll
  for (int i = 0; i < 2; i++) {
    const int s = rl + i * 32;
    short8 v = *(const short8*)&Vp[((size_t)bh * S_ + s0 + s) * DH_ + u * 8];
#pragma unroll
    for (int j = 0; j < 8; j++) T[(u * 8 + j) * 72 + s] = (unsigned short)v[j];
  }
  __syncthreads();
#pragma unroll
  for (int i = 0; i < 2; i++) {
    const int d = rl + i * 32;
    short8 o = *(const short8*)&T[d * 72 + u * 8];
    *(short8*)&Vt[((size_t)bh * DH_ + d) * S_ + s0 + u * 8] = o;
  }
}

// ---------------------------------------------------------------- attention
// grid (32 q-tiles, 48 bh), 256 thr = 4 waves x 16 q-rows. KV tile = 32 keys.
__global__ __launch_bounds__(256) void attn_kernel(
    const unsigned short* __restrict__ Qp, const unsigned short* __restrict__ Kp,
    const unsigned short* __restrict__ Vt, const int* __restrict__ mask,
    unsigned short* __restrict__ Ctx) {
  __shared__ unsigned short Ks[32 * 64];      // [key][d], XOR-swizzled 16B units
  __shared__ unsigned short Vs[64 * 40];      // [d][key], padded rows
  __shared__ unsigned short Ps[4 * 16 * 40];  // per-wave P [16 q][32 key], padded
  __shared__ float maskf[32];

  const int bh = blockIdx.y, b = bh / NH_, h = bh % NH_;
  const int q0 = blockIdx.x * 64;
  const int tid = threadIdx.x, w = tid >> 6, l = tid & 63;
  const int lr = l & 15, lg = l >> 4;

  // Q fragments (A-operand): row = lr, k = lg*8 (+32)
  const unsigned short* Qbase = Qp + ((size_t)bh * S_ + q0 + w * 16 + lr) * DH_;
  const short8 aq0 = *(const short8*)(Qbase + lg * 8);
  const short8 aq1 = *(const short8*)(Qbase + lg * 8 + 32);

  float m_run[4], l_run[4];
  f32x4 ctx[4] = {};
#pragma unroll
  for (int r = 0; r < 4; r++) { m_run[r] = -INFINITY; l_run[r] = 0.f; }

  const int krow = tid >> 3, ku = tid & 7;  // K staging: key row, 16B unit
  const int vd = tid >> 2,  vu = tid & 3;   // V staging: d row, 16B unit
  const unsigned short* Kg = Kp + ((size_t)bh * S_ + krow) * DH_ + ku * 8;
  const unsigned short* Vg = Vt + ((size_t)bh * DH_ + vd) * S_ + vu * 8;
  unsigned short* Pw = Ps + w * 16 * 40;

  for (int kt = 0; kt < S_ / 32; kt++) {
    const int kv0 = kt * 32;
    // issue global loads early (overlap with previous-tile drain)
    const short8 kreg = *(const short8*)(Kg + (size_t)kv0 * DH_);
    const short8 vreg = *(const short8*)(Vg + kv0);
    int mreg = 0;
    if (tid < 32) mreg = mask[b * S_ + kv0 + tid];
    __syncthreads();
    *(short8*)&Ks[krow * 64 + ((ku ^ (krow & 7)) * 8)] = kreg;
    *(short8*)&Vs[vd * 40 + vu * 8] = vreg;
    if (tid < 32) maskf[tid] = mreg ? 0.f : -1e30f;
    __syncthreads();

    // S = Q K^T  (two 16-key column tiles)
    f32x4 sacc[2] = {};
#pragma unroll
    for (int c = 0; c < 2; c++) {
      const int row = c * 16 + lr;
#pragma unroll
      for (int kk = 0; kk < 2; kk++) {
        const int du = lg + kk * 4;
        short8 bk = *(const short8*)&Ks[row * 64 + ((du ^ (row & 7)) * 8)];
        sacc[c] = __builtin_amdgcn_mfma_f32_16x16x32_bf16(kk == 0 ? aq0 : aq1, bk,
                                                          sacc[c], 0, 0, 0);
      }
    }
    // key-padding mask
    const float mk0 = maskf[lr], mk1 = maskf[16 + lr];
#pragma unroll
    for (int r = 0; r < 4; r++) { sacc[0][r] += mk0; sacc[1][r] += mk1; }

    // online softmax (row = lg*4 + r, keys across lr lanes)
    float alpha[4];
#pragma unroll
    for (int r = 0; r < 4; r++) {
      float t = fmaxf(sacc[0][r], sacc[1][r]);
      t = fmaxf(t, __shfl_xor(t, 1));
      t = fmaxf(t, __shfl_xor(t, 2));
      t = fmaxf(t, __shfl_xor(t, 4));
      t = fmaxf(t, __shfl_xor(t, 8));
      const float nm = fmaxf(m_run[r], t);
      alpha[r] = __expf(m_run[r] - nm);
      m_run[r] = nm;
      const float p0 = __expf(sacc[0][r] - nm);
      const float p1 = __expf(sacc[1][r] - nm);
      sacc[0][r] = p0; sacc[1][r] = p1;
      float ts = p0 + p1;
      ts += __shfl_xor(ts, 1);
      ts += __shfl_xor(ts, 2);
      ts += __shfl_xor(ts, 4);
      ts += __shfl_xor(ts, 8);
      l_run[r] = l_run[r] * alpha[r] + ts;
    }
#pragma unroll
    for (int dt = 0; dt < 4; dt++)
#pragma unroll
      for (int r = 0; r < 4; r++) ctx[dt][r] *= alpha[r];

    // P -> LDS (re-layout to A-fragment), then PV
#pragma unroll
    for (int c = 0; c < 2; c++)
#pragma unroll
      for (int r = 0; r < 4; r++)
        Pw[(lg * 4 + r) * 40 + c * 16 + lr] = f2bf(sacc[c][r]);
    const short8 pa = *(const short8*)&Pw[lr * 40 + lg * 8];
#pragma unroll
    for (int dt = 0; dt < 4; dt++) {
      short8 bv = *(const short8*)&Vs[(dt * 16 + lr) * 40 + lg * 8];
      ctx[dt] = __builtin_amdgcn_mfma_f32_16x16x32_bf16(pa, bv, ctx[dt], 0, 0, 0);
    }
  }

  // epilogue: normalize, write [B,S,768] bf16
#pragma unroll
  for (int r = 0; r < 4; r++) {
    const float inv = 1.f / l_run[r];
    const int qg = q0 + w * 16 + lg * 4 + r;
#pragma unroll
    for (int dt = 0; dt < 4; dt++) {
      Ctx[((size_t)b * S_ + qg) * D_ + h * DH_ + dt * 16 + lr] =
          f2bf(ctx[dt][r] * inv);
    }
  }
}

// ---------------------------------------------------------------- launcher
extern "C" void kernel_launch(void* const* d_in, const int* in_sizes, int n_in,
                              void* d_out, int out_size, void* d_ws, size_t ws_size,
                              hipStream_t stream) {
  const float* q   = (const float*)d_in[0];
  const float* k   = (const float*)d_in[1];
  const float* v   = (const float*)d_in[2];
  const int* mask  = (const int*)d_in[3];
  const float* q_w = (const float*)d_in[4];
  const float* q_b = (const float*)d_in[5];
  const float* k_w = (const float*)d_in[6];
  const float* k_b = (const float*)d_in[7];
  const float* v_w = (const float*)d_in[8];
  const float* v_b = (const float*)d_in[9];
  const float* o_w = (const float*)d_in[10];
  const float* o_b = (const float*)d_in[11];
  float* out = (float*)d_out;

  unsigned short* ws = (unsigned short*)d_ws;
  unsigned short* Xq = ws;
  unsigned short* Xk = Xq + NX;
  unsigned short* Xv = Xk + NX;
  unsigned short* Wq = Xv + NX;
  unsigned short* Wk = Wq + NW;
  unsigned short* Wv = Wk + NW;
  unsigned short* Wo = Wv + NW;
  unsigned short* Qp = Wo + NW;
  unsigned short* Kp = Qp + NX;
  unsigned short* Vp = Kp + NX;
  unsigned short* Vt  = Xk;  // alias: Xk dead after its GEMM
  unsigned short* Ctx = Xq;  // alias: Xq dead after its GEMM

  convert_kernel<<<dim3(6144, 7), dim3(256), 0, stream>>>(
      q, k, v, q_w, k_w, v_w, o_w, Xq, Xk, Xv, Wq, Wk, Wv, Wo);

  qkv_gemm<<<dim3(64, 6, 3), dim3(256), 0, stream>>>(
      Xq, Xk, Xv, Wq, Wk, Wv, q_b, k_b, v_b, Qp, Kp, Vp);

  transpose_v<<<dim3(32, 48), dim3(256), 0, stream>>>(Vp, Vt);

  attn_kernel<<<dim3(32, 48), dim3(256), 0, stream>>>(Qp, Kp, Vt, mask, Ctx);

  out_gemm<<<dim3(64, 6), dim3(256), 0, stream>>>(Ctx, Wo, o_b, out);
}